// Round 4
// baseline (679.588 us; speedup 1.0000x reference)
//
#include <hip/hip_runtime.h>
#include <hip/hip_bf16.h>
#include <math.h>

#define NEMB 256
#define DIM 64
#define SIGS 128
#define THREADS 512
#define NSIG 131072
#define GRID (NSIG / SIGS)

#define LOG1P50 3.9318256327243257        // np.log1p(50.0), f64
#define INV_MU_F ((float)(1.0 / LOG1P50)) // fp32-rounded scalar, as numpy uses
#define TWO15_F ((float)(2.0 / 15.0))

// dynamic LDS layout (byte offsets)
#define LB_DN    0          // 65536 B : Dn f32 [c][n]
#define LB_SIG   65536      // 32768 B : sig f32 [c][w]
#define LB_QV    98304      // 2048 B  : qv f32 [4][SIGS]
#define LB_QI    100352     // 2048 B  : qi i32 [4][SIGS]
#define LB_RED   102400     // 64 B    : per-wave loss partials (f64)
#define LDS_BYTES 102464

// nrm: fp32, squares rounded individually, SEQUENTIAL sum over c (numpy
// axis-0 reduce order), sqrtf, fmaxf, fp32 divide — mirrors np.linalg.norm.
__global__ void k_normalize(const float* __restrict__ D, float* __restrict__ Dn)
{
#pragma clang fp contract(off)
    int n = threadIdx.x;   // one thread per column, 256 threads
    float ss = 0.0f;
    for (int c = 0; c < DIM; c++) {
        float v = D[c * NEMB + n];
        float sq = v * v;
        ss = ss + sq;
    }
    float nrm = fmaxf(sqrtf(ss), 1e-10f);
    for (int c = 0; c < DIM; c++)
        Dn[c * NEMB + n] = D[c * NEMB + n] / nrm;
}

// G = Dn^T Dn: fp32, fused-FMA sequential over k ascending (BLAS sgemm order)
__global__ void k_gram(const float* __restrict__ Dn, float* __restrict__ G)
{
    __shared__ float coli[DIM];
    int i = blockIdx.x, j = threadIdx.x;
    if (j < DIM) coli[j] = Dn[j * NEMB + i];
    __syncthreads();
    float s = 0.0f;
#pragma unroll
    for (int c = 0; c < DIM; c++) s = fmaf(coli[c], Dn[c * NEMB + j], s);
    G[i * NEMB + j] = s;
}

// mu-law quantize+decode, all fp32, numpy op-for-op (no fusion)
__device__ __forceinline__ float quant_decode(float coeff)
{
#pragma clang fp contract(off)
    float c = fminf(fmaxf(coeff, -3.0f), 3.0f) / 3.0f;
    float ac = fabsf(c);
    float sgn = (c > 0.0f) ? 1.0f : ((c < 0.0f) ? -1.0f : 0.0f);
    float l = log1pf(ac * 50.0f);
    float enc = (sgn * l) * INV_MU_F;
    float scaled = (enc + 1.0f) * 7.5f;
    int bin = (int)rintf(scaled);              // round-half-even == np.round
    bin = bin < 0 ? 0 : (bin > 15 ? 15 : bin);
    float t = (float)bin * TWO15_F;
    float zv = t - 1.0f;
    float az = fabsf(zv);
    float sz = (zv > 0.0f) ? 1.0f : ((zv < 0.0f) ? -1.0f : 0.0f);
    float e = expm1f(az / INV_MU_F);
    return (sz * (e / 50.0f)) * 3.0f;
}

// One signal's OMP (K=4), executed redundantly by all 64 lanes of a wave.
// Lane l owns atoms 4l..4l+3. Full fp32, numpy-order: dot-style sums
// (ascending, separately rounded), subtract, divide. No FMA.
__device__ __forceinline__ void omp_signal(const float* hb4, int lane,
                                           const float* __restrict__ G,
                                           float* __restrict__ qv,
                                           int* __restrict__ qi, int s)
{
#pragma clang fp contract(off)
    float hbsi[4] = {hb4[0], hb4[1], hb4[2], hb4[3]};
    float h[4] = {hbsi[0], hbsi[1], hbsi[2], hbsi[3]};
    float Lm[4][4];
    float Gr[3][4];
    int Iv[4];
    float hsel[4];
    float xs[4];
    float y[4];
    int m4 = 0;
#pragma unroll
    for (int kk = 0; kk < 4; kk++) {
        // ---- argmax(|h| * ~mask), numpy first-index tie-break ----
        float bv = -1.0f;
        int bi = 0;
#pragma unroll
        for (int j = 0; j < 4; j++) {
            float v = (m4 & (1 << j)) ? 0.0f : fabsf(h[j]);
            if (v > bv) { bv = v; bi = 4 * lane + j; }
        }
#pragma unroll
        for (int off = 1; off < 64; off <<= 1) {
            float ov = __shfl_xor(bv, off);
            int oi = __shfl_xor(bi, off);
            if (ov > bv || (ov == bv && oi < bi)) { bv = ov; bi = oi; }
        }
        int idx = bi;                 // wave-uniform
        int owner = idx >> 2;
        int slot = idx & 3;
        if (owner == lane) m4 |= (1 << slot);
        // cache G row for this atom (float4/lane, coalesced, L2-hot)
        if (kk < 3) {
            const float4 gt = *(const float4*)(G + (size_t)idx * NEMB + 4 * lane);
            Gr[kk][0] = gt.x; Gr[kk][1] = gt.y; Gr[kk][2] = gt.z; Gr[kk][3] = gt.w;
        }
        // ---- Cholesky row update ----
        if (kk > 0) {
            float Gs[3], w[3];
#pragma unroll
            for (int j = 0; j < 3; j++) {
                if (j < kk) {
                    float tv = (slot == 0) ? Gr[j][0] : ((slot == 1) ? Gr[j][1] : ((slot == 2) ? Gr[j][2] : Gr[j][3]));
                    Gs[j] = __shfl(tv, owner);   // G[I_j, idx]
                }
            }
            // forward substitution: w[r] = (G[r] - sum_{c<r} L*w)/L[r][r]
#pragma unroll
            for (int r = 0; r < 3; r++) {
                if (r < kk) {
                    float acc = 0.0f;
#pragma unroll
                    for (int cc = 0; cc < 3; cc++)
                        if (cc < r) { float p = Lm[r][cc] * w[cc]; acc = acc + p; }
                    float t2 = Gs[r] - acc;
                    w[r] = t2 / Lm[r][r];
                }
            }
            float ssum = 0.0f;
#pragma unroll
            for (int j = 0; j < 3; j++)
                if (j < kk) { float p = w[j] * w[j]; ssum = ssum + p; }
            float om = 1.0f - ssum;
            float wc = sqrtf(fmaxf(om, 1e-12f));
#pragma unroll
            for (int cc = 0; cc < 3; cc++)
                if (cc < kk) Lm[kk][cc] = w[cc];
            Lm[kk][kk] = wc;
        } else {
            Lm[0][0] = 1.0f;
        }
        Iv[kk] = idx;
        {
            float tv = (slot == 0) ? hbsi[0] : ((slot == 1) ? hbsi[1] : ((slot == 2) ? hbsi[2] : hbsi[3]));
            hsel[kk] = __shfl(tv, owner);        // h_bar[idx]
        }
        // ---- forward solve L y = hsel ----
#pragma unroll
        for (int r = 0; r < 4; r++) {
            if (r <= kk) {
                float acc = 0.0f;
#pragma unroll
                for (int cc = 0; cc < 4; cc++)
                    if (cc < r) { float p = Lm[r][cc] * y[cc]; acc = acc + p; }
                float t2 = hsel[r] - acc;
                y[r] = t2 / Lm[r][r];
            }
        }
        // ---- backward solve L^T x = y (sum ascending c>r) ----
#pragma unroll
        for (int r = 3; r >= 0; r--) {
            if (r <= kk) {
                float acc = 0.0f;
#pragma unroll
                for (int cc = 0; cc < 4; cc++)
                    if (cc > r && cc <= kk) { float p = Lm[cc][r] * xs[cc]; acc = acc + p; }
                float t2 = y[r] - acc;
                xs[r] = t2 / Lm[r][r];
            }
        }
        // ---- residual: h = h_bar - einsum(x, G[I]) (no fma, k ascending) ----
        if (kk < 3) {
#pragma unroll
            for (int j = 0; j < 4; j++) {
                float bsum = 0.0f;
#pragma unroll
                for (int jj = 0; jj < 3; jj++)
                    if (jj <= kk) { float p = xs[jj] * Gr[jj][j]; bsum = bsum + p; }
                h[j] = hbsi[j] - bsum;
            }
        }
    }
    if (lane == 0) {
#pragma unroll
        for (int j = 0; j < 4; j++) {
            qv[j * SIGS + s] = quant_decode(xs[j]);
            qi[j * SIGS + s] = Iv[j];
        }
    }
}

__launch_bounds__(THREADS, 2)
__global__ void k_omp(const float* __restrict__ z,
                      const float* __restrict__ Dn_g,
                      const float* __restrict__ G,
                      double* __restrict__ loss_acc,
                      float* __restrict__ zq)
{
    extern __shared__ char smem[];
    float* Dn = (float*)(smem + LB_DN);
    float* sig = (float*)(smem + LB_SIG);
    float* qv = (float*)(smem + LB_QV);
    int* qi = (int*)(smem + LB_QI);
    double* red = (double*)(smem + LB_RED);

    int tid = threadIdx.x;
    int lane = tid & 63;
    int wid = tid >> 6;

    // stage Dn f32 into LDS (float4, coalesced)
    {
        const float4* src = (const float4*)Dn_g;
        float4* dst = (float4*)Dn;
#pragma unroll
        for (int i = 0; i < 8; i++) dst[i * THREADS + tid] = src[i * THREADS + tid];
    }

    long sbase = (long)blockIdx.x * SIGS;   // 128 consecutive pixels, one batch b
    int b = (int)(sbase >> 12);
    int pl0 = (int)(sbase & 4095);
    const float* zb = z + ((size_t)b << 18) + pl0;
    // stage z_e -> sig[c][w], coalesced along w
    {
        int w = tid & (SIGS - 1);
        int g = tid >> 7;
#pragma unroll
        for (int i = 0; i < 16; i++) {
            int c = g * 16 + i;
            sig[c * SIGS + w] = zb[(size_t)c * 4096 + w];
        }
    }
    __syncthreads();

    // each wave: 16 signals in 2 groups of 8; h_bar = X^T Dn, fp32 fused-FMA
    // sequential over c ascending (BLAS sgemm accumulation order)
    for (int g2 = 0; g2 < 2; g2++) {
        int s0 = wid * 16 + g2 * 8;
        float hb[8][4];
#pragma unroll
        for (int a = 0; a < 8; a++)
#pragma unroll
            for (int t = 0; t < 4; t++) hb[a][t] = 0.0f;
        for (int c = 0; c < DIM; c++) {
            float4 sva = *(const float4*)(sig + c * SIGS + s0);
            float4 svb = *(const float4*)(sig + c * SIGS + s0 + 4);
            float s8[8] = {sva.x, sva.y, sva.z, sva.w, svb.x, svb.y, svb.z, svb.w};
            float4 dv = *(const float4*)(Dn + c * NEMB + 4 * lane);
            float d4[4] = {dv.x, dv.y, dv.z, dv.w};
#pragma unroll
            for (int a = 0; a < 8; a++) {
                hb[a][0] = fmaf(s8[a], d4[0], hb[a][0]);
                hb[a][1] = fmaf(s8[a], d4[1], hb[a][1]);
                hb[a][2] = fmaf(s8[a], d4[2], hb[a][2]);
                hb[a][3] = fmaf(s8[a], d4[3], hb[a][3]);
            }
        }
#pragma unroll
        for (int a = 0; a < 8; a++)
            omp_signal(hb[a], lane, G, qv, qi, s0 + a);
    }
    __syncthreads();

    // store phase: recon (einsum order: mul+add, k ascending, no fma),
    // z_q = z_e + (recon - z_e), loss accumulated in f64
    double lsum = 0.0;
    float* zqb = zq + ((size_t)b << 18) + pl0;
    {
#pragma clang fp contract(off)
        int w = tid & (SIGS - 1);
        int g = tid >> 7;
        float q0 = qv[0 * SIGS + w], q1 = qv[1 * SIGS + w];
        float q2 = qv[2 * SIGS + w], q3 = qv[3 * SIGS + w];
        int i0 = qi[0 * SIGS + w], i1 = qi[1 * SIGS + w];
        int i2 = qi[2 * SIGS + w], i3 = qi[3 * SIGS + w];
#pragma unroll
        for (int ci = 0; ci < 16; ci++) {
            int c = g * 16 + ci;
            const float* dr = Dn + c * NEMB;
            float p0 = q0 * dr[i0];
            float p1 = q1 * dr[i1];
            float p2 = q2 * dr[i2];
            float p3 = q3 * dr[i3];
            float r = p0 + p1;
            r = r + p2;
            r = r + p3;
            float zev = sig[c * SIGS + w];
            float d = r - zev;
            float zqv = zev + d;           // z_q = z_e + (recon - z_e)
            lsum += (double)d * (double)d;
            zqb[(size_t)c * 4096 + w] = zqv;
        }
    }
#pragma unroll
    for (int off = 32; off > 0; off >>= 1) lsum += __shfl_xor(lsum, off);
    if (lane == 0) red[wid] = lsum;
    __syncthreads();
    if (tid == 0) {
        double t = 0.0;
#pragma unroll
        for (int i = 0; i < 8; i++) t += red[i];
        atomicAdd(loss_acc, t);
    }
}

__global__ void k_final(const double* __restrict__ loss_acc, float* __restrict__ out)
{
    double m = loss_acc[0] / 8388608.0;      // mean((recon - z_e)^2)
    out[0] = (float)(m + 0.25 * m);          // q_loss + 0.25*e_loss
}

extern "C" void kernel_launch(void* const* d_in, const int* in_sizes, int n_in,
                              void* d_out, int out_size, void* d_ws, size_t ws_size,
                              hipStream_t stream)
{
    const float* z = (const float*)d_in[0];
    const float* D = (const float*)d_in[1];
    float* out = (float*)d_out;
    char* ws = (char*)d_ws;
    double* loss_acc = (double*)ws;              // 8 B
    float* Dn = (float*)(ws + 256);              // 64x256 f32
    float* G = (float*)(ws + 256 + 65536);       // 256x256 f32

    hipMemsetAsync(loss_acc, 0, sizeof(double), stream);
    k_normalize<<<1, NEMB, 0, stream>>>(D, Dn);
    k_gram<<<NEMB, NEMB, 0, stream>>>(Dn, G);
    hipFuncSetAttribute(reinterpret_cast<const void*>(k_omp),
                        hipFuncAttributeMaxDynamicSharedMemorySize, LDS_BYTES);
    k_omp<<<GRID, THREADS, LDS_BYTES, stream>>>(z, Dn, G, loss_acc, out);
    k_final<<<1, 1, 0, stream>>>(loss_acc, out + 8388608);
    (void)in_sizes; (void)n_in; (void)out_size; (void)ws_size;
}

// Round 5
// 301.413 us; speedup vs baseline: 2.2547x; 2.2547x over previous
//
#include <hip/hip_runtime.h>
#include <math.h>

#define NEMB 256
#define DIM 64
#define SIGS 128
#define THREADS 512
#define NSIG 131072
#define GRID (NSIG / SIGS)

#define LOG1P50 3.9318256327243257        // np.log1p(50.0), f64
#define INV_MU_F ((float)(1.0 / LOG1P50)) // fp32-rounded scalar, as numpy uses
#define TWO15_F ((float)(2.0 / 15.0))

// dynamic LDS layout (byte offsets) — Dn NOT staged (L2-hot from global):
// 37 KB/block -> 3-4 blocks/CU instead of 1 (was 102 KB)
#define LB_SIG   0          // 32768 B : sig f32 [c][w]
#define LB_XS    32768      // 2048 B  : raw coeffs f32 [4][SIGS] (quantized in-place)
#define LB_QI    34816      // 2048 B  : qi i32 [4][SIGS]
#define LB_RED   36864      // 64 B    : per-wave loss partials (f64)
#define LDS_BYTES 36928

// nrm: fp32, squares rounded individually, sequential sum over c, mirrors np.
__global__ void k_normalize(const float* __restrict__ D, float* __restrict__ Dn)
{
#pragma clang fp contract(off)
    int n = threadIdx.x;   // one thread per column, 256 threads
    float ss = 0.0f;
    for (int c = 0; c < DIM; c++) {
        float v = D[c * NEMB + n];
        float sq = v * v;
        ss = ss + sq;
    }
    float nrm = fmaxf(sqrtf(ss), 1e-10f);
    for (int c = 0; c < DIM; c++)
        Dn[c * NEMB + n] = D[c * NEMB + n] / nrm;
}

// G = Dn^T Dn: fp32, fused-FMA sequential over k ascending (BLAS sgemm order)
__global__ void k_gram(const float* __restrict__ Dn, float* __restrict__ G)
{
    __shared__ float coli[DIM];
    int i = blockIdx.x, j = threadIdx.x;
    if (j < DIM) coli[j] = Dn[j * NEMB + i];
    __syncthreads();
    float s = 0.0f;
#pragma unroll
    for (int c = 0; c < DIM; c++) s = fmaf(coli[c], Dn[c * NEMB + j], s);
    G[i * NEMB + j] = s;
}

// mu-law quantize+decode, all fp32, numpy op-for-op (no fusion)
__device__ __forceinline__ float quant_decode(float coeff)
{
#pragma clang fp contract(off)
    float c = fminf(fmaxf(coeff, -3.0f), 3.0f) / 3.0f;
    float ac = fabsf(c);
    float sgn = (c > 0.0f) ? 1.0f : ((c < 0.0f) ? -1.0f : 0.0f);
    float l = log1pf(ac * 50.0f);
    float enc = (sgn * l) * INV_MU_F;
    float scaled = (enc + 1.0f) * 7.5f;
    int bin = (int)rintf(scaled);              // round-half-even == np.round
    bin = bin < 0 ? 0 : (bin > 15 ? 15 : bin);
    float t = (float)bin * TWO15_F;
    float zv = t - 1.0f;
    float az = fabsf(zv);
    float sz = (zv > 0.0f) ? 1.0f : ((zv < 0.0f) ? -1.0f : 0.0f);
    float e = expm1f(az / INV_MU_F);
    return (sz * (e / 50.0f)) * 3.0f;
}

// One signal's OMP (K=4), all 64 lanes of a wave cooperate; lane l owns
// atoms 4l..4l+3. Bit-exact vs round-4 passing version; cheaper mechanics:
//  - argmax: value-only shfl_xor max-reduce + ballot/ffsll (lowest lane =
//    numpy first-index tie-break), 7 ds ops instead of 12
//  - G[I_j, idx] via wave-uniform (readfirstlane) loads -> scalar pipe
//  - forward solve incremental (rows 0..k-1 bit-identical across iters)
//  - quantization deferred to a thread-parallel pass (raw xs to LDS)
__device__ __forceinline__ void omp_signal(const float* hb4, int lane,
                                           const float* __restrict__ G,
                                           float* __restrict__ xsv,
                                           int* __restrict__ qi, int s)
{
#pragma clang fp contract(off)
    float hbsi[4] = {hb4[0], hb4[1], hb4[2], hb4[3]};
    float h[4] = {hbsi[0], hbsi[1], hbsi[2], hbsi[3]};
    float Lm[4][4];
    float Gr[3][4];
    int Iv[4];
    float hsel[4];
    float xs[4];
    float y[4];
    int m4 = 0;
#pragma unroll
    for (int kk = 0; kk < 4; kk++) {
        // ---- per-lane best of own 4 atoms (first-index within lane) ----
        float bv = -1.0f;
        int bj = 0;
#pragma unroll
        for (int j = 0; j < 4; j++) {
            float v = (m4 & (1 << j)) ? 0.0f : fabsf(h[j]);
            if (v > bv) { bv = v; bj = j; }
        }
        // ---- wave max (value only) ----
        float vmax = bv;
#pragma unroll
        for (int off = 1; off < 64; off <<= 1)
            vmax = fmaxf(vmax, __shfl_xor(vmax, off));
        // ---- first lane holding the max = numpy first-index tie-break ----
        unsigned long long mball = __ballot(bv == vmax);
        int owner = __ffsll(mball) - 1;
        int idx = __shfl(4 * lane + bj, owner);
        idx = __builtin_amdgcn_readfirstlane(idx);   // SGPR: enables s_loads
        if (lane == owner) m4 |= (1 << bj);
        // cache G row for this atom (float4/lane, coalesced, L2-hot)
        if (kk < 3) {
            const float4 gt = *(const float4*)(G + (size_t)idx * NEMB + 4 * lane);
            Gr[kk][0] = gt.x; Gr[kk][1] = gt.y; Gr[kk][2] = gt.z; Gr[kk][3] = gt.w;
        }
        // ---- Cholesky row update ----
        if (kk > 0) {
            float Gs[3], w[3];
#pragma unroll
            for (int j = 0; j < 3; j++)
                if (j < kk) Gs[j] = G[(size_t)Iv[j] * NEMB + idx];  // uniform -> s_load
#pragma unroll
            for (int r = 0; r < 3; r++) {
                if (r < kk) {
                    float acc = 0.0f;
#pragma unroll
                    for (int cc = 0; cc < 3; cc++)
                        if (cc < r) { float p = Lm[r][cc] * w[cc]; acc = acc + p; }
                    float t2 = Gs[r] - acc;
                    w[r] = t2 / Lm[r][r];
                }
            }
            float ssum = 0.0f;
#pragma unroll
            for (int j = 0; j < 3; j++)
                if (j < kk) { float p = w[j] * w[j]; ssum = ssum + p; }
            float om = 1.0f - ssum;
            float wc = sqrtf(fmaxf(om, 1e-12f));
#pragma unroll
            for (int cc = 0; cc < 3; cc++)
                if (cc < kk) Lm[kk][cc] = w[cc];
            Lm[kk][kk] = wc;
        } else {
            Lm[0][0] = 1.0f;
        }
        Iv[kk] = idx;
        {
            float tv = (bj == 0) ? hbsi[0] : ((bj == 1) ? hbsi[1] : ((bj == 2) ? hbsi[2] : hbsi[3]));
            hsel[kk] = __shfl(tv, owner);        // h_bar[idx]
        }
        // ---- forward solve, incremental: only row kk is new ----
        {
            float acc = 0.0f;
#pragma unroll
            for (int cc = 0; cc < 3; cc++)
                if (cc < kk) { float p = Lm[kk][cc] * y[cc]; acc = acc + p; }
            float t2 = hsel[kk] - acc;
            y[kk] = t2 / Lm[kk][kk];
        }
        // ---- backward solve L^T x = y (full, sum ascending c>r) ----
#pragma unroll
        for (int r = 3; r >= 0; r--) {
            if (r <= kk) {
                float acc = 0.0f;
#pragma unroll
                for (int cc = 0; cc < 4; cc++)
                    if (cc > r && cc <= kk) { float p = Lm[cc][r] * xs[cc]; acc = acc + p; }
                float t2 = y[r] - acc;
                xs[r] = t2 / Lm[r][r];
            }
        }
        // ---- residual: h = h_bar - einsum(x, G[I]) (no fma, k ascending) ----
        if (kk < 3) {
#pragma unroll
            for (int j = 0; j < 4; j++) {
                float bsum = 0.0f;
#pragma unroll
                for (int jj = 0; jj < 3; jj++)
                    if (jj <= kk) { float p = xs[jj] * Gr[jj][j]; bsum = bsum + p; }
                h[j] = hbsi[j] - bsum;
            }
        }
    }
    if (lane == 0) {
#pragma unroll
        for (int j = 0; j < 4; j++) {
            xsv[j * SIGS + s] = xs[j];   // raw coeff; quantized later in parallel
            qi[j * SIGS + s] = Iv[j];
        }
    }
}

__launch_bounds__(THREADS, 6)
__global__ void k_omp(const float* __restrict__ z,
                      const float* __restrict__ Dn_g,
                      const float* __restrict__ G,
                      double* __restrict__ loss_acc,
                      float* __restrict__ zq)
{
    extern __shared__ char smem[];
    float* sig = (float*)(smem + LB_SIG);
    float* xsv = (float*)(smem + LB_XS);
    int* qi = (int*)(smem + LB_QI);
    double* red = (double*)(smem + LB_RED);

    int tid = threadIdx.x;
    int lane = tid & 63;
    int wid = tid >> 6;

    long sbase = (long)blockIdx.x * SIGS;   // 128 consecutive pixels, one batch b
    int b = (int)(sbase >> 12);
    int pl0 = (int)(sbase & 4095);
    const float* zb = z + ((size_t)b << 18) + pl0;
    // stage z_e -> sig[c][w], coalesced along w
    {
        int w = tid & (SIGS - 1);
        int g = tid >> 7;
#pragma unroll
        for (int i = 0; i < 16; i++) {
            int c = g * 16 + i;
            sig[c * SIGS + w] = zb[(size_t)c * 4096 + w];
        }
    }
    __syncthreads();

    // each wave: 16 signals in 2 groups of 8; h_bar = X^T Dn, fp32 fused-FMA
    // sequential over c ascending. Dn read from global (64 KB, L1/L2-hot).
    for (int g2 = 0; g2 < 2; g2++) {
        int s0 = wid * 16 + g2 * 8;
        float hb[8][4];
#pragma unroll
        for (int a = 0; a < 8; a++)
#pragma unroll
            for (int t = 0; t < 4; t++) hb[a][t] = 0.0f;
#pragma unroll 8
        for (int c = 0; c < DIM; c++) {
            float4 sva = *(const float4*)(sig + c * SIGS + s0);
            float4 svb = *(const float4*)(sig + c * SIGS + s0 + 4);
            float s8[8] = {sva.x, sva.y, sva.z, sva.w, svb.x, svb.y, svb.z, svb.w};
            float4 dv = *(const float4*)(Dn_g + c * NEMB + 4 * lane);
            float d4[4] = {dv.x, dv.y, dv.z, dv.w};
#pragma unroll
            for (int a = 0; a < 8; a++) {
                hb[a][0] = fmaf(s8[a], d4[0], hb[a][0]);
                hb[a][1] = fmaf(s8[a], d4[1], hb[a][1]);
                hb[a][2] = fmaf(s8[a], d4[2], hb[a][2]);
                hb[a][3] = fmaf(s8[a], d4[3], hb[a][3]);
            }
        }
#pragma unroll
        for (int a = 0; a < 8; a++)
            omp_signal(hb[a], lane, G, xsv, qi, s0 + a);
    }
    __syncthreads();

    // thread-parallel mu-law quantize of all 512 coeffs (was serial per signal)
    {
        int jq = tid >> 7;
        int wq = tid & (SIGS - 1);
        xsv[jq * SIGS + wq] = quant_decode(xsv[jq * SIGS + wq]);
    }
    __syncthreads();

    // store phase: recon (einsum order: mul+add, k ascending, no fma),
    // z_q = z_e + (recon - z_e), loss accumulated in f64
    double lsum = 0.0;
    float* zqb = zq + ((size_t)b << 18) + pl0;
    {
#pragma clang fp contract(off)
        int w = tid & (SIGS - 1);
        int g = tid >> 7;
        float q0 = xsv[0 * SIGS + w], q1 = xsv[1 * SIGS + w];
        float q2 = xsv[2 * SIGS + w], q3 = xsv[3 * SIGS + w];
        int i0 = qi[0 * SIGS + w], i1 = qi[1 * SIGS + w];
        int i2 = qi[2 * SIGS + w], i3 = qi[3 * SIGS + w];
#pragma unroll
        for (int ci = 0; ci < 16; ci++) {
            int c = g * 16 + ci;
            const float* dr = Dn_g + c * NEMB;
            float p0 = q0 * dr[i0];
            float p1 = q1 * dr[i1];
            float p2 = q2 * dr[i2];
            float p3 = q3 * dr[i3];
            float r = p0 + p1;
            r = r + p2;
            r = r + p3;
            float zev = sig[c * SIGS + w];
            float d = r - zev;
            float zqv = zev + d;           // z_q = z_e + (recon - z_e)
            lsum += (double)d * (double)d;
            zqb[(size_t)c * 4096 + w] = zqv;
        }
    }
#pragma unroll
    for (int off = 32; off > 0; off >>= 1) lsum += __shfl_xor(lsum, off);
    if (lane == 0) red[wid] = lsum;
    __syncthreads();
    if (tid == 0) {
        double t = 0.0;
#pragma unroll
        for (int i = 0; i < 8; i++) t += red[i];
        atomicAdd(loss_acc, t);
    }
}

__global__ void k_final(const double* __restrict__ loss_acc, float* __restrict__ out)
{
    double m = loss_acc[0] / 8388608.0;      // mean((recon - z_e)^2)
    out[0] = (float)(m + 0.25 * m);          // q_loss + 0.25*e_loss
}

extern "C" void kernel_launch(void* const* d_in, const int* in_sizes, int n_in,
                              void* d_out, int out_size, void* d_ws, size_t ws_size,
                              hipStream_t stream)
{
    const float* z = (const float*)d_in[0];
    const float* D = (const float*)d_in[1];
    float* out = (float*)d_out;
    char* ws = (char*)d_ws;
    double* loss_acc = (double*)ws;              // 8 B
    float* Dn = (float*)(ws + 256);              // 64x256 f32
    float* G = (float*)(ws + 256 + 65536);       // 256x256 f32

    hipMemsetAsync(loss_acc, 0, sizeof(double), stream);
    k_normalize<<<1, NEMB, 0, stream>>>(D, Dn);
    k_gram<<<NEMB, NEMB, 0, stream>>>(Dn, G);
    hipFuncSetAttribute(reinterpret_cast<const void*>(k_omp),
                        hipFuncAttributeMaxDynamicSharedMemorySize, LDS_BYTES);
    k_omp<<<GRID, THREADS, LDS_BYTES, stream>>>(z, Dn, G, loss_acc, out);
    k_final<<<1, 1, 0, stream>>>(loss_acc, out + 8388608);
    (void)in_sizes; (void)n_in; (void)out_size; (void)ws_size;
}